// Round 3
// baseline (246.112 us; speedup 1.0000x reference)
//
#include <hip/hip_runtime.h>

#define Nn 512
#define NNe 262144
#define CST 546   // padded column stride (>= pidx(511)+1 = 546)

__device__ __forceinline__ float2 f2(float x, float y){ return make_float2(x, y); }
__device__ __forceinline__ float2 cadd(float2 a, float2 b){ return f2(a.x+b.x, a.y+b.y); }
__device__ __forceinline__ float2 csub(float2 a, float2 b){ return f2(a.x-b.x, a.y-b.y); }
__device__ __forceinline__ float2 cmul(float2 a, float2 b){
    return f2(a.x*b.x - a.y*b.y, a.x*b.y + a.y*b.x);
}
// LDS padding: spreads banks across all three radix-8 stage access patterns
__device__ __forceinline__ int pidx(int p){ return p + (p>>4) + (p>>7); }
// intra-wave fence: LDS ops of one wave execute in program order; this only
// stops the compiler from reordering across the phase boundary. No s_barrier.
#define WFENCE() __builtin_amdgcn_wave_barrier()

// 8-point DFT (symmetric matrix). SGN=-1: forward, SGN=+1: inverse kernel (no 1/N)
template<int SGN>
__device__ __forceinline__ void fft8(float2 a[8]){
    const float r = 0.7071067811865476f;
    const float S = (float)SGN;
    float2 u0 = cadd(a[0], a[4]), u1 = cadd(a[1], a[5]);
    float2 u2 = cadd(a[2], a[6]), u3 = cadd(a[3], a[7]);
    float2 v0 = csub(a[0], a[4]), v1 = csub(a[1], a[5]);
    float2 v2 = csub(a[2], a[6]), v3 = csub(a[3], a[7]);
    v1 = cmul(v1, f2(r, S*r));
    v2 = cmul(v2, f2(0.f, S));
    v3 = cmul(v3, f2(-r, S*r));
    float2 p0 = cadd(u0, u2), p1 = cadd(u1, u3);
    float2 q0 = csub(u0, u2), q1 = cmul(csub(u1, u3), f2(0.f, S));
    a[0] = cadd(p0, p1); a[4] = csub(p0, p1);
    a[2] = cadd(q0, q1); a[6] = csub(q0, q1);
    p0 = cadd(v0, v2); p1 = cadd(v1, v3);
    q0 = csub(v0, v2); q1 = cmul(csub(v1, v3), f2(0.f, S));
    a[1] = cadd(p0, p1); a[5] = csub(p0, p1);
    a[3] = cadd(q0, q1); a[7] = csub(q0, q1);
}

template<int SGN>
__device__ __forceinline__ float2 twd(int idx, float inv){
    float ang = ((float)SGN) * 6.283185307179586f * (inv * (float)idx);
    float s, c;
    __sincosf(ang, &s, &c);
    return f2(c, s);
}

// DIF radix-8^3, 512-pt, per-wave. In: v[q] = x[lane+64q] (natural).
// Out (REGISTERS): v[k2] = X[64*k2 + 8*(lane&7) + (lane>>3)]  (tau-permuted).
// buf is wave-private LDS scratch; 2 internal LDS round trips, no barriers.
template<int SGN>
__device__ void fft512_dif(float2 v[8], float2* buf, int lane){
    fft8<SGN>(v);
    {
        float2 w1 = twd<SGN>(lane, 1.f/512.f);
        float2 w  = f2(1.f, 0.f);
        #pragma unroll
        for (int r = 0; r < 8; ++r){
            buf[pidx(r*64 + lane)] = cmul(v[r], w);
            w = cmul(w, w1);
        }
    }
    WFENCE();
    int rb = (lane >> 3) * 64, t2 = lane & 7;
    float2 y[8];
    #pragma unroll
    for (int q = 0; q < 8; ++q) y[q] = buf[pidx(rb + t2 + 8*q)];
    fft8<SGN>(y);
    WFENCE();
    {
        float2 w2 = twd<SGN>(t2, 1.f/64.f);
        float2 w  = f2(1.f, 0.f);
        #pragma unroll
        for (int r = 0; r < 8; ++r){
            buf[pidx(rb + r*8 + t2)] = cmul(y[r], w);
            w = cmul(w, w2);
        }
    }
    WFENCE();
    int base = rb + t2*8;
    #pragma unroll
    for (int q = 0; q < 8; ++q) v[q] = buf[pidx(base + q)];
    fft8<SGN>(v);
    // v[k2] = X[64k2 + 8*(lane&7) + (lane>>3)] — left tau-permuted in regs
}

// DIT (transposed DIF network): In (REGISTERS): v[k2] = u[64*k2 + 8*(lane&7) + (lane>>3)].
// Out: v[q] = X[lane + 64q] (natural). Same twiddle diagonals (DFT8 symmetric).
template<int SGN>
__device__ void fft512_dit(float2 v[8], float2* buf, int lane){
    int rb = (lane >> 3) * 64, t2 = lane & 7;
    fft8<SGN>(v);                         // transpose of DIF stage 3
    int base = rb + t2*8;
    #pragma unroll
    for (int q = 0; q < 8; ++q) buf[pidx(base + q)] = v[q];
    WFENCE();
    float2 y[8];
    #pragma unroll
    for (int r = 0; r < 8; ++r) y[r] = buf[pidx(rb + r*8 + t2)];
    {
        float2 w2 = twd<SGN>(t2, 1.f/64.f);
        float2 w  = f2(1.f, 0.f);
        #pragma unroll
        for (int r = 0; r < 8; ++r){
            y[r] = cmul(y[r], w);
            w = cmul(w, w2);
        }
    }
    fft8<SGN>(y);
    WFENCE();
    #pragma unroll
    for (int q = 0; q < 8; ++q) buf[pidx(rb + t2 + 8*q)] = y[q];
    WFENCE();
    #pragma unroll
    for (int r = 0; r < 8; ++r) v[r] = buf[pidx(r*64 + lane)];
    {
        float2 w1 = twd<SGN>(lane, 1.f/512.f);
        float2 w  = f2(1.f, 0.f);
        #pragma unroll
        for (int r = 0; r < 8; ++r){
            v[r] = cmul(v[r], w);
            w = cmul(w, w1);
        }
    }
    fft8<SGN>(v);                         // v[q] = X[lane + 64q] natural
}

// K1: temp[kj] = row-IFFT( x_hat * psi_hat[kj] ), one wave per row.
// Store tau-permuted registers directly: slot 64k2+lane (coalesced). No barriers.
__global__ __launch_bounds__(256)
void k_mulrow(const float2* __restrict__ xh, const float* __restrict__ pr,
              const float* __restrict__ pi, float2* __restrict__ temp){
    __shared__ float2 lds[4][548];
    int wave = threadIdx.x >> 6, lane = threadIdx.x & 63;
    int img  = blockIdx.x >> 7;
    int row  = ((blockIdx.x & 127) << 2) | wave;
    size_t boff = (size_t)img * NNe + (size_t)row * Nn;
    const float2* xr = xh + (size_t)row * Nn;
    float2 v[8];
    #pragma unroll
    for (int q = 0; q < 8; ++q){
        int x = lane + 64*q;
        float2 xv = xr[x];
        float2 pv = f2(pr[boff + x], pi[boff + x]);
        v[q] = cmul(xv, pv);
    }
    fft512_dif<1>(v, lds[wave], lane);
    float2* outp = temp + boff;
    #pragma unroll
    for (int q = 0; q < 8; ++q) outp[64*q + lane] = v[q];
}

// K2 (fused): col-IFFT + modulus + col-FFT, in place on temp.
// 8-column tiles; wave-private columns; only 2 block barriers.
__global__ __launch_bounds__(256)
void k_colfused(float2* __restrict__ temp){
    __shared__ float2 tile[8 * CST];
    int img = blockIdx.x >> 6;
    int x0  = (blockIdx.x & 63) << 3;
    float2* src = temp + (size_t)img * NNe + x0;
    for (int i = threadIdx.x; i < 512*4; i += 256){
        int yy = i >> 2, c2 = (i & 3) << 1;
        float4 v = *(const float4*)&src[(size_t)yy * Nn + c2];
        tile[c2*CST + pidx(yy)]     = f2(v.x, v.y);
        tile[(c2+1)*CST + pidx(yy)] = f2(v.z, v.w);
    }
    __syncthreads();
    int wave = threadIdx.x >> 6, lane = threadIdx.x & 63;
    const float sc = 3.814697265625e-06f;   // 1/NN (ifft2 normalization)
    #pragma unroll 1
    for (int cc = 0; cc < 2; ++cc){
        int c = (wave << 1) | cc;
        float2* buf = &tile[c * CST];
        float2 v[8];
        #pragma unroll
        for (int q = 0; q < 8; ++q) v[q] = buf[pidx(lane + 64*q)];
        fft512_dif<1>(v, buf, lane);        // col IFFT -> tau-permuted regs
        #pragma unroll
        for (int q = 0; q < 8; ++q){        // modulus (pointwise, order-free)
            float re = v[q].x * sc, im = v[q].y * sc;
            v[q] = f2(sqrtf(re*re + im*im + 1e-8f), 0.f);
        }
        WFENCE();
        fft512_dit<-1>(v, buf, lane);       // col FFT -> natural regs
        #pragma unroll
        for (int q = 0; q < 8; ++q) buf[pidx(lane + 64*q)] = v[q];
        WFENCE();
    }
    __syncthreads();
    for (int i = threadIdx.x; i < 512*4; i += 256){
        int yy = i >> 2, c2 = (i & 3) << 1;
        float2 a = tile[c2*CST + pidx(yy)];
        float2 b = tile[(c2+1)*CST + pidx(yy)];
        *(float4*)&src[(size_t)yy * Nn + c2] = make_float4(a.x, a.y, b.x, b.y);
    }
}

// K3: row FFT + |.|^2 -> power. Loads tau-slots, DIT back to natural. No barriers.
__global__ __launch_bounds__(256)
void k_rowpow(const float2* __restrict__ temp, float* __restrict__ power){
    __shared__ float2 lds[4][548];
    int wave = threadIdx.x >> 6, lane = threadIdx.x & 63;
    int img  = blockIdx.x >> 7;
    int row  = ((blockIdx.x & 127) << 2) | wave;
    const float2* src = temp + (size_t)img * NNe + (size_t)row * Nn;
    float2 v[8];
    #pragma unroll
    for (int q = 0; q < 8; ++q) v[q] = src[64*q + lane];
    fft512_dit<-1>(v, lds[wave], lane);
    float* dst = power + (size_t)img * NNe + (size_t)row * Nn;
    #pragma unroll
    for (int q = 0; q < 8; ++q)
        dst[lane + 64*q] = v[q].x*v[q].x + v[q].y*v[q].y;
}

// s0 partials
__global__ __launch_bounds__(256)
void k_s0(const float2* __restrict__ xh, const float* __restrict__ phr,
          const float* __restrict__ phii, float* __restrict__ part){
    int gid = blockIdx.x*256 + threadIdx.x;
    float acc = 0.f;
    for (int n = gid; n < NNe; n += 256*256){
        float2 x = xh[n];
        float a = phr[n], b = phii[n];
        acc += (x.x*x.x + x.y*x.y) * (a*a + b*b);
    }
    #pragma unroll
    for (int o = 32; o > 0; o >>= 1) acc += __shfl_down(acc, o, 64);
    __shared__ float wsum[4];
    int wave = threadIdx.x >> 6, lane = threadIdx.x & 63;
    if (lane == 0) wsum[wave] = acc;
    __syncthreads();
    if (threadIdx.x == 0) part[blockIdx.x] = wsum[0]+wsum[1]+wsum[2]+wsum[3];
}

// K5: C[48][49] = power[48][NN] x {psi2, phi2}[NN][49]; per-wave LDS, 6x7 register tiles,
// deterministic per-wave partials (1024 slices, stride 2400 = 48*50)
__global__ __launch_bounds__(128)
void k_gemm(const float* __restrict__ power, const float* __restrict__ pr,
            const float* __restrict__ pi, const float* __restrict__ phr,
            const float* __restrict__ phii, float* __restrict__ partC){
    __shared__ __align__(16) float P[2][48][68];
    __shared__ __align__(16) float W[2][56][68];
    int wave = threadIdx.x >> 6, lane = threadIdx.x & 63;
    float (*Pw)[68] = P[wave];
    float (*Ww)[68] = W[wave];
    int gw = blockIdx.x*2 + wave;           // 0..1023
    int lm = lane >> 3, lw = lane & 7;
    float acc[6][7] = {};
    #pragma unroll
    for (int r = 49; r < 56; ++r){          // zero W pad rows once
        Ww[r][lane] = 0.f;
        if (lane < 4) Ww[r][64 + lane] = 0.f;
    }
    int n0 = gw * 256;
    for (int st = 0; st < 4; ++st){
        int nb = n0 + st*64;
        __syncthreads();
        #pragma unroll
        for (int rr = 0; rr < 12; ++rr){
            int row = rr*4 + (lane >> 4);
            int c4  = (lane & 15) * 4;
            float4 v = *(const float4*)&power[(size_t)row*NNe + nb + c4];
            *(float4*)&Pw[row][c4] = v;
        }
        #pragma unroll
        for (int rr = 0; rr < 12; ++rr){
            int row = rr*4 + (lane >> 4);
            int c4  = (lane & 15) * 4;
            size_t off = (size_t)row*NNe + nb + c4;
            float4 a = *(const float4*)&pr[off];
            float4 b = *(const float4*)&pi[off];
            float4 w4;
            w4.x = a.x*a.x + b.x*b.x; w4.y = a.y*a.y + b.y*b.y;
            w4.z = a.z*a.z + b.z*b.z; w4.w = a.w*a.w + b.w*b.w;
            *(float4*)&Ww[row][c4] = w4;
        }
        if (lane < 16){
            int c4 = lane * 4;
            float4 a = *(const float4*)&phr[nb + c4];
            float4 b = *(const float4*)&phii[nb + c4];
            float4 w4;
            w4.x = a.x*a.x + b.x*b.x; w4.y = a.y*a.y + b.y*b.y;
            w4.z = a.z*a.z + b.z*b.z; w4.w = a.w*a.w + b.w*b.w;
            *(float4*)&Ww[48][c4] = w4;
        }
        __syncthreads();
        #pragma unroll 2
        for (int nn = 0; nn < 64; nn += 4){
            float4 pa[6], wb[7];
            #pragma unroll
            for (int i = 0; i < 6; ++i) pa[i] = *(const float4*)&Pw[lm + 8*i][nn];
            #pragma unroll
            for (int j = 0; j < 7; ++j) wb[j] = *(const float4*)&Ww[lw + 8*j][nn];
            #pragma unroll
            for (int i = 0; i < 6; ++i)
                #pragma unroll
                for (int j = 0; j < 7; ++j){
                    float s = acc[i][j];
                    s = fmaf(pa[i].x, wb[j].x, s);
                    s = fmaf(pa[i].y, wb[j].y, s);
                    s = fmaf(pa[i].z, wb[j].z, s);
                    s = fmaf(pa[i].w, wb[j].w, s);
                    acc[i][j] = s;
                }
        }
    }
    float* outp = partC + (size_t)gw * 2400;
    #pragma unroll
    for (int i = 0; i < 6; ++i)
        #pragma unroll
        for (int j = 0; j < 7; ++j){
            int m = lm + 8*i, wc = lw + 8*j;
            if (wc < 49) outp[m*50 + wc] = acc[i][j];
        }
}

// reduce 1024 partial C slices -> CF[2400]
__global__ __launch_bounds__(256)
void k_redc(const float* __restrict__ partC, float* __restrict__ CF){
    __shared__ float red[4][64];
    int e0 = blockIdx.x * 64;
    int es = threadIdx.x & 63, bq = threadIdx.x >> 6;
    int e = e0 + es;
    float s = 0.f;
    if (e < 2400)
        for (int b = bq; b < 1024; b += 4) s += partC[(size_t)b*2400 + e];
    red[bq][es] = s;
    __syncthreads();
    if (bq == 0 && e < 2400) CF[e] = red[0][es]+red[1][es]+red[2][es]+red[3][es];
}

// final: s0 + assemble 1009-element output in torch-loop concatenation order
__global__ __launch_bounds__(256)
void k_final(const float* __restrict__ CF, const float* __restrict__ partS0,
             float* __restrict__ outp, float SC){
    __shared__ float ssum[4];
    int tid = threadIdx.x, wave = tid >> 6, lane = tid & 63;
    float a = partS0[tid];
    #pragma unroll
    for (int o = 32; o > 0; o >>= 1) a += __shfl_down(a, o, 64);
    if (lane == 0) ssum[wave] = a;
    __syncthreads();
    if (tid == 0) outp[0] = SC * (ssum[0]+ssum[1]+ssum[2]+ssum[3]);
    int off = 1;
    for (int i = 0; i < 6; ++i){
        if (tid < 8) outp[off + tid] = SC * CF[(tid*6 + i)*50 + 48];   // a[:, i]
        off += 8;
        if (i < 5){
            int nj = 5 - i, cnt = 64 * nj;
            for (int p = tid; p < cnt; p += 256){
                int j2 = p % nj;
                int km = p / nj;
                int m = km & 7, k = km >> 3;
                outp[off + p] = SC * CF[(k*6 + i)*50 + m*6 + (i + 1 + j2)];
            }
            off += cnt;
        }
    }
}

extern "C" void kernel_launch(void* const* d_in, const int* in_sizes, int n_in,
                              void* d_out, int out_size, void* d_ws, size_t ws_size,
                              hipStream_t stream){
    (void)in_sizes; (void)n_in; (void)out_size; (void)ws_size;
    const float2* xh  = (const float2*)d_in[0];
    const float*  phr = (const float*)d_in[1];
    const float*  phi_= (const float*)d_in[2];
    const float*  psr = (const float*)d_in[3];
    const float*  psi_= (const float*)d_in[4];
    float* outp = (float*)d_out;
    float* ws   = (float*)d_ws;

    // workspace layout (f32 units): power[48*NN] | partC[1024*2400] | s0[256] | CF[2400] | temp[48*NN*2]
    size_t o_power = 0;
    size_t o_partC = o_power + (size_t)48 * NNe;
    size_t o_s0    = o_partC + (size_t)1024 * 2400;
    size_t o_CF    = o_s0 + 256;
    size_t o_temp  = o_CF + 2400;                         // even -> float2 aligned
    float*  power = ws + o_power;
    float*  partC = ws + o_partC;
    float*  ps0   = ws + o_s0;
    float*  CF    = ws + o_CF;
    float2* temp  = (float2*)(ws + o_temp);

    const float SC = (float)(1.0 / (4.0 * 3.14159265358979323846 * 3.14159265358979323846)
                             / (double)NNe);              // INV / NN

    k_s0<<<dim3(256), dim3(256), 0, stream>>>(xh, phr, phi_, ps0);
    k_mulrow<<<dim3(48*128), dim3(256), 0, stream>>>(xh, psr, psi_, temp);
    k_colfused<<<dim3(48*64), dim3(256), 0, stream>>>(temp);
    k_rowpow<<<dim3(48*128), dim3(256), 0, stream>>>(temp, power);
    k_gemm<<<dim3(512), dim3(128), 0, stream>>>(power, psr, psi_, phr, phi_, partC);
    k_redc<<<dim3(38), dim3(256), 0, stream>>>(partC, CF);
    k_final<<<dim3(1), dim3(256), 0, stream>>>(CF, ps0, outp, SC);
}

// Round 4
// 222.679 us; speedup vs baseline: 1.1052x; 1.1052x over previous
//
#include <hip/hip_runtime.h>
#include <hip/hip_fp16.h>

#define Nn 512
#define NNe 262144
#define CST 546   // padded column stride (>= pidx(511)+1 = 546)

__device__ __forceinline__ float2 f2(float x, float y){ return make_float2(x, y); }
__device__ __forceinline__ float2 cadd(float2 a, float2 b){ return f2(a.x+b.x, a.y+b.y); }
__device__ __forceinline__ float2 csub(float2 a, float2 b){ return f2(a.x-b.x, a.y-b.y); }
__device__ __forceinline__ float2 cmul(float2 a, float2 b){
    return f2(a.x*b.x - a.y*b.y, a.x*b.y + a.y*b.x);
}
// LDS padding: spreads banks across all three radix-8 stage access patterns
__device__ __forceinline__ int pidx(int p){ return p + (p>>4) + (p>>7); }
// intra-wave fence: LDS ops of one wave execute in program order; this only
// stops the compiler from reordering across the phase boundary. No s_barrier.
#define WFENCE() __builtin_amdgcn_wave_barrier()

// 8-point DFT (symmetric matrix). SGN=-1: forward, SGN=+1: inverse kernel (no 1/N)
template<int SGN>
__device__ __forceinline__ void fft8(float2 a[8]){
    const float r = 0.7071067811865476f;
    const float S = (float)SGN;
    float2 u0 = cadd(a[0], a[4]), u1 = cadd(a[1], a[5]);
    float2 u2 = cadd(a[2], a[6]), u3 = cadd(a[3], a[7]);
    float2 v0 = csub(a[0], a[4]), v1 = csub(a[1], a[5]);
    float2 v2 = csub(a[2], a[6]), v3 = csub(a[3], a[7]);
    v1 = cmul(v1, f2(r, S*r));
    v2 = cmul(v2, f2(0.f, S));
    v3 = cmul(v3, f2(-r, S*r));
    float2 p0 = cadd(u0, u2), p1 = cadd(u1, u3);
    float2 q0 = csub(u0, u2), q1 = cmul(csub(u1, u3), f2(0.f, S));
    a[0] = cadd(p0, p1); a[4] = csub(p0, p1);
    a[2] = cadd(q0, q1); a[6] = csub(q0, q1);
    p0 = cadd(v0, v2); p1 = cadd(v1, v3);
    q0 = csub(v0, v2); q1 = cmul(csub(v1, v3), f2(0.f, S));
    a[1] = cadd(p0, p1); a[5] = csub(p0, p1);
    a[3] = cadd(q0, q1); a[7] = csub(q0, q1);
}

template<int SGN>
__device__ __forceinline__ float2 twd(int idx, float inv){
    float ang = ((float)SGN) * 6.283185307179586f * (inv * (float)idx);
    float s, c;
    __sincosf(ang, &s, &c);
    return f2(c, s);
}

// DIF radix-8^3, 512-pt, per-wave. In: v[q] = x[lane+64q] (natural).
// Out (REGISTERS): v[k2] = X[64*k2 + 8*(lane&7) + (lane>>3)]  (tau-permuted).
template<int SGN>
__device__ void fft512_dif(float2 v[8], float2* buf, int lane){
    fft8<SGN>(v);
    {
        float2 w1 = twd<SGN>(lane, 1.f/512.f);
        float2 w  = f2(1.f, 0.f);
        #pragma unroll
        for (int r = 0; r < 8; ++r){
            buf[pidx(r*64 + lane)] = cmul(v[r], w);
            w = cmul(w, w1);
        }
    }
    WFENCE();
    int rb = (lane >> 3) * 64, t2 = lane & 7;
    float2 y[8];
    #pragma unroll
    for (int q = 0; q < 8; ++q) y[q] = buf[pidx(rb + t2 + 8*q)];
    fft8<SGN>(y);
    WFENCE();
    {
        float2 w2 = twd<SGN>(t2, 1.f/64.f);
        float2 w  = f2(1.f, 0.f);
        #pragma unroll
        for (int r = 0; r < 8; ++r){
            buf[pidx(rb + r*8 + t2)] = cmul(y[r], w);
            w = cmul(w, w2);
        }
    }
    WFENCE();
    int base = rb + t2*8;
    #pragma unroll
    for (int q = 0; q < 8; ++q) v[q] = buf[pidx(base + q)];
    fft8<SGN>(v);
    // v[k2] = X[64k2 + 8*(lane&7) + (lane>>3)] — left tau-permuted in regs
}

// DIT (transposed DIF network): In (REGISTERS): v[k2] = u[64*k2 + 8*(lane&7) + (lane>>3)].
// Out: v[q] = X[lane + 64q] (natural).
template<int SGN>
__device__ void fft512_dit(float2 v[8], float2* buf, int lane){
    int rb = (lane >> 3) * 64, t2 = lane & 7;
    fft8<SGN>(v);
    int base = rb + t2*8;
    #pragma unroll
    for (int q = 0; q < 8; ++q) buf[pidx(base + q)] = v[q];
    WFENCE();
    float2 y[8];
    #pragma unroll
    for (int r = 0; r < 8; ++r) y[r] = buf[pidx(rb + r*8 + t2)];
    {
        float2 w2 = twd<SGN>(t2, 1.f/64.f);
        float2 w  = f2(1.f, 0.f);
        #pragma unroll
        for (int r = 0; r < 8; ++r){
            y[r] = cmul(y[r], w);
            w = cmul(w, w2);
        }
    }
    fft8<SGN>(y);
    WFENCE();
    #pragma unroll
    for (int q = 0; q < 8; ++q) buf[pidx(rb + t2 + 8*q)] = y[q];
    WFENCE();
    #pragma unroll
    for (int r = 0; r < 8; ++r) v[r] = buf[pidx(r*64 + lane)];
    {
        float2 w1 = twd<SGN>(lane, 1.f/512.f);
        float2 w  = f2(1.f, 0.f);
        #pragma unroll
        for (int r = 0; r < 8; ++r){
            v[r] = cmul(v[r], w);
            w = cmul(w, w1);
        }
    }
    fft8<SGN>(v);
}

// K1: temp[kj] = row-IFFT( x_hat * psi_hat[kj] ) stored fp16 tau-permuted;
// also emits psi2 = |psi|^2 as fp16 (natural order) for the GEMM.
__global__ __launch_bounds__(256, 6)
void k_mulrow(const float2* __restrict__ xh, const float* __restrict__ pr,
              const float* __restrict__ pi, __half2* __restrict__ temp,
              __half* __restrict__ psi2h){
    __shared__ float2 lds[4][548];
    int wave = threadIdx.x >> 6, lane = threadIdx.x & 63;
    int img  = blockIdx.x >> 7;
    int row  = ((blockIdx.x & 127) << 2) | wave;
    size_t boff = (size_t)img * NNe + (size_t)row * Nn;
    const float2* xr = xh + (size_t)row * Nn;
    float2 v[8];
    #pragma unroll
    for (int q = 0; q < 8; ++q){
        int x = lane + 64*q;
        float2 xv = xr[x];
        float2 pv = f2(pr[boff + x], pi[boff + x]);
        psi2h[boff + x] = __float2half_rn(pv.x*pv.x + pv.y*pv.y);
        v[q] = cmul(xv, pv);
    }
    fft512_dif<1>(v, lds[wave], lane);
    __half2* outp = temp + boff;
    #pragma unroll
    for (int q = 0; q < 8; ++q) outp[64*q + lane] = __floats2half2_rn(v[q].x, v[q].y);
}

// K2 (fused): col-IFFT + modulus + col-FFT, in place on fp16 temp.
// 8-column tiles, 8 waves (one column per wave); 2 block barriers.
__global__ __launch_bounds__(512, 6)
void k_colfused(__half2* __restrict__ temp){
    __shared__ float2 tile[8 * CST];
    int img = blockIdx.x >> 6;
    int x0  = (blockIdx.x & 63) << 3;
    __half2* srcH = temp + (size_t)img * NNe + x0;
    for (int i = threadIdx.x; i < 1024; i += 512){
        int yy = i >> 1, c4 = (i & 1) << 2;
        uint4 u = *(const uint4*)&srcH[(size_t)yy * Nn + c4];
        tile[(c4+0)*CST + pidx(yy)] = __half22float2(*(__half2*)&u.x);
        tile[(c4+1)*CST + pidx(yy)] = __half22float2(*(__half2*)&u.y);
        tile[(c4+2)*CST + pidx(yy)] = __half22float2(*(__half2*)&u.z);
        tile[(c4+3)*CST + pidx(yy)] = __half22float2(*(__half2*)&u.w);
    }
    __syncthreads();
    int wave = threadIdx.x >> 6, lane = threadIdx.x & 63;
    const float sc = 3.814697265625e-06f;   // 1/NN (ifft2 normalization)
    {
        float2* buf = &tile[wave * CST];
        float2 v[8];
        #pragma unroll
        for (int q = 0; q < 8; ++q) v[q] = buf[pidx(lane + 64*q)];
        fft512_dif<1>(v, buf, lane);        // col IFFT -> tau-permuted regs
        #pragma unroll
        for (int q = 0; q < 8; ++q){        // modulus (pointwise, order-free)
            float re = v[q].x * sc, im = v[q].y * sc;
            v[q] = f2(sqrtf(re*re + im*im + 1e-8f), 0.f);
        }
        WFENCE();
        fft512_dit<-1>(v, buf, lane);       // col FFT -> natural regs
        #pragma unroll
        for (int q = 0; q < 8; ++q) buf[pidx(lane + 64*q)] = v[q];
    }
    __syncthreads();
    for (int i = threadIdx.x; i < 1024; i += 512){
        int yy = i >> 1, c4 = (i & 1) << 2;
        uint4 u;
        float2 a0 = tile[(c4+0)*CST + pidx(yy)];
        float2 a1 = tile[(c4+1)*CST + pidx(yy)];
        float2 a2 = tile[(c4+2)*CST + pidx(yy)];
        float2 a3 = tile[(c4+3)*CST + pidx(yy)];
        *(__half2*)&u.x = __floats2half2_rn(a0.x, a0.y);
        *(__half2*)&u.y = __floats2half2_rn(a1.x, a1.y);
        *(__half2*)&u.z = __floats2half2_rn(a2.x, a2.y);
        *(__half2*)&u.w = __floats2half2_rn(a3.x, a3.y);
        *(uint4*)&srcH[(size_t)yy * Nn + c4] = u;
    }
}

// K3: row FFT + |.|^2 -> power (f32). Loads fp16 tau-slots, DIT to natural.
__global__ __launch_bounds__(256, 6)
void k_rowpow(const __half2* __restrict__ temp, float* __restrict__ power){
    __shared__ float2 lds[4][548];
    int wave = threadIdx.x >> 6, lane = threadIdx.x & 63;
    int img  = blockIdx.x >> 7;
    int row  = ((blockIdx.x & 127) << 2) | wave;
    const __half2* src = temp + (size_t)img * NNe + (size_t)row * Nn;
    float2 v[8];
    #pragma unroll
    for (int q = 0; q < 8; ++q) v[q] = __half22float2(src[64*q + lane]);
    fft512_dit<-1>(v, lds[wave], lane);
    float* dst = power + (size_t)img * NNe + (size_t)row * Nn;
    #pragma unroll
    for (int q = 0; q < 8; ++q)
        dst[lane + 64*q] = v[q].x*v[q].x + v[q].y*v[q].y;
}

// s0 partials
__global__ __launch_bounds__(256)
void k_s0(const float2* __restrict__ xh, const float* __restrict__ phr,
          const float* __restrict__ phii, float* __restrict__ part){
    int gid = blockIdx.x*256 + threadIdx.x;
    float acc = 0.f;
    for (int n = gid; n < NNe; n += 256*256){
        float2 x = xh[n];
        float a = phr[n], b = phii[n];
        acc += (x.x*x.x + x.y*x.y) * (a*a + b*b);
    }
    #pragma unroll
    for (int o = 32; o > 0; o >>= 1) acc += __shfl_down(acc, o, 64);
    __shared__ float wsum[4];
    int wave = threadIdx.x >> 6, lane = threadIdx.x & 63;
    if (lane == 0) wsum[wave] = acc;
    __syncthreads();
    if (threadIdx.x == 0) part[blockIdx.x] = wsum[0]+wsum[1]+wsum[2]+wsum[3];
}

// K5: C[48][49] = power[48][NN] x {psi2, phi2}[NN][49]; psi2 from fp16.
__global__ __launch_bounds__(128)
void k_gemm(const float* __restrict__ power, const __half* __restrict__ psi2h,
            const float* __restrict__ phr, const float* __restrict__ phii,
            float* __restrict__ partC){
    __shared__ __align__(16) float P[2][48][68];
    __shared__ __align__(16) float W[2][56][68];
    int wave = threadIdx.x >> 6, lane = threadIdx.x & 63;
    float (*Pw)[68] = P[wave];
    float (*Ww)[68] = W[wave];
    int gw = blockIdx.x*2 + wave;           // 0..1023
    int lm = lane >> 3, lw = lane & 7;
    float acc[6][7] = {};
    #pragma unroll
    for (int r = 49; r < 56; ++r){          // zero W pad rows once
        Ww[r][lane] = 0.f;
        if (lane < 4) Ww[r][64 + lane] = 0.f;
    }
    int n0 = gw * 256;
    for (int st = 0; st < 4; ++st){
        int nb = n0 + st*64;
        __syncthreads();
        #pragma unroll
        for (int rr = 0; rr < 12; ++rr){
            int row = rr*4 + (lane >> 4);
            int c4  = (lane & 15) * 4;
            float4 v = *(const float4*)&power[(size_t)row*NNe + nb + c4];
            *(float4*)&Pw[row][c4] = v;
        }
        #pragma unroll
        for (int rr = 0; rr < 12; ++rr){
            int row = rr*4 + (lane >> 4);
            int c4  = (lane & 15) * 4;
            size_t off = (size_t)row*NNe + nb + c4;
            const __half2* p2 = (const __half2*)&psi2h[off];
            float2 f0 = __half22float2(p2[0]);
            float2 f1 = __half22float2(p2[1]);
            *(float4*)&Ww[row][c4] = make_float4(f0.x, f0.y, f1.x, f1.y);
        }
        if (lane < 16){
            int c4 = lane * 4;
            float4 a = *(const float4*)&phr[nb + c4];
            float4 b = *(const float4*)&phii[nb + c4];
            float4 w4;
            w4.x = a.x*a.x + b.x*b.x; w4.y = a.y*a.y + b.y*b.y;
            w4.z = a.z*a.z + b.z*b.z; w4.w = a.w*a.w + b.w*b.w;
            *(float4*)&Ww[48][c4] = w4;
        }
        __syncthreads();
        #pragma unroll 2
        for (int nn = 0; nn < 64; nn += 4){
            float4 pa[6], wb[7];
            #pragma unroll
            for (int i = 0; i < 6; ++i) pa[i] = *(const float4*)&Pw[lm + 8*i][nn];
            #pragma unroll
            for (int j = 0; j < 7; ++j) wb[j] = *(const float4*)&Ww[lw + 8*j][nn];
            #pragma unroll
            for (int i = 0; i < 6; ++i)
                #pragma unroll
                for (int j = 0; j < 7; ++j){
                    float s = acc[i][j];
                    s = fmaf(pa[i].x, wb[j].x, s);
                    s = fmaf(pa[i].y, wb[j].y, s);
                    s = fmaf(pa[i].z, wb[j].z, s);
                    s = fmaf(pa[i].w, wb[j].w, s);
                    acc[i][j] = s;
                }
        }
    }
    float* outp = partC + (size_t)gw * 2400;
    #pragma unroll
    for (int i = 0; i < 6; ++i)
        #pragma unroll
        for (int j = 0; j < 7; ++j){
            int m = lm + 8*i, wc = lw + 8*j;
            if (wc < 49) outp[m*50 + wc] = acc[i][j];
        }
}

// reduce 1024 partial C slices -> CF[2400]
__global__ __launch_bounds__(256)
void k_redc(const float* __restrict__ partC, float* __restrict__ CF){
    __shared__ float red[4][64];
    int e0 = blockIdx.x * 64;
    int es = threadIdx.x & 63, bq = threadIdx.x >> 6;
    int e = e0 + es;
    float s = 0.f;
    if (e < 2400)
        for (int b = bq; b < 1024; b += 4) s += partC[(size_t)b*2400 + e];
    red[bq][es] = s;
    __syncthreads();
    if (bq == 0 && e < 2400) CF[e] = red[0][es]+red[1][es]+red[2][es]+red[3][es];
}

// final: s0 + assemble 1009-element output in torch-loop concatenation order
__global__ __launch_bounds__(256)
void k_final(const float* __restrict__ CF, const float* __restrict__ partS0,
             float* __restrict__ outp, float SC){
    __shared__ float ssum[4];
    int tid = threadIdx.x, wave = tid >> 6, lane = tid & 63;
    float a = partS0[tid];
    #pragma unroll
    for (int o = 32; o > 0; o >>= 1) a += __shfl_down(a, o, 64);
    if (lane == 0) ssum[wave] = a;
    __syncthreads();
    if (tid == 0) outp[0] = SC * (ssum[0]+ssum[1]+ssum[2]+ssum[3]);
    int off = 1;
    for (int i = 0; i < 6; ++i){
        if (tid < 8) outp[off + tid] = SC * CF[(tid*6 + i)*50 + 48];   // a[:, i]
        off += 8;
        if (i < 5){
            int nj = 5 - i, cnt = 64 * nj;
            for (int p = tid; p < cnt; p += 256){
                int j2 = p % nj;
                int km = p / nj;
                int m = km & 7, k = km >> 3;
                outp[off + p] = SC * CF[(k*6 + i)*50 + m*6 + (i + 1 + j2)];
            }
            off += cnt;
        }
    }
}

extern "C" void kernel_launch(void* const* d_in, const int* in_sizes, int n_in,
                              void* d_out, int out_size, void* d_ws, size_t ws_size,
                              hipStream_t stream){
    (void)in_sizes; (void)n_in; (void)out_size; (void)ws_size;
    const float2* xh  = (const float2*)d_in[0];
    const float*  phr = (const float*)d_in[1];
    const float*  phi_= (const float*)d_in[2];
    const float*  psr = (const float*)d_in[3];
    const float*  psi_= (const float*)d_in[4];
    float* outp = (float*)d_out;
    float* ws   = (float*)d_ws;

    // ws layout (f32 units): power[48NN] | partC[1024*2400] | s0[256] | CF[2400] |
    //                        temp(half2)[48NN] | psi2(half)[24NN]
    size_t o_power = 0;
    size_t o_partC = o_power + (size_t)48 * NNe;
    size_t o_s0    = o_partC + (size_t)1024 * 2400;
    size_t o_CF    = o_s0 + 256;
    size_t o_temp  = o_CF + 2400;
    size_t o_psi2  = o_temp + (size_t)48 * NNe;
    float*   power = ws + o_power;
    float*   partC = ws + o_partC;
    float*   ps0   = ws + o_s0;
    float*   CF    = ws + o_CF;
    __half2* temp  = (__half2*)(ws + o_temp);
    __half*  psi2h = (__half*)(ws + o_psi2);

    const float SC = (float)(1.0 / (4.0 * 3.14159265358979323846 * 3.14159265358979323846)
                             / (double)NNe);              // INV / NN

    k_s0<<<dim3(256), dim3(256), 0, stream>>>(xh, phr, phi_, ps0);
    k_mulrow<<<dim3(48*128), dim3(256), 0, stream>>>(xh, psr, psi_, temp, psi2h);
    k_colfused<<<dim3(48*64), dim3(512), 0, stream>>>(temp);
    k_rowpow<<<dim3(48*128), dim3(256), 0, stream>>>(temp, power);
    k_gemm<<<dim3(512), dim3(128), 0, stream>>>(power, psi2h, phr, phi_, partC);
    k_redc<<<dim3(38), dim3(256), 0, stream>>>(partC, CF);
    k_final<<<dim3(1), dim3(256), 0, stream>>>(CF, ps0, outp, SC);
}

// Round 5
// 158.231 us; speedup vs baseline: 1.5554x; 1.4073x over previous
//
#include <hip/hip_runtime.h>
#include <hip/hip_fp16.h>

#define Nn 512
#define NNe 262144
#define CST 546   // padded column stride (>= pidx(511)+1 = 546)

__device__ __forceinline__ float2 f2(float x, float y){ return make_float2(x, y); }
__device__ __forceinline__ float2 cadd(float2 a, float2 b){ return f2(a.x+b.x, a.y+b.y); }
__device__ __forceinline__ float2 csub(float2 a, float2 b){ return f2(a.x-b.x, a.y-b.y); }
__device__ __forceinline__ float2 cmul(float2 a, float2 b){
    return f2(a.x*b.x - a.y*b.y, a.x*b.y + a.y*b.x);
}
// LDS padding: spreads banks across all three radix-8 stage access patterns
__device__ __forceinline__ int pidx(int p){ return p + (p>>4) + (p>>7); }
// intra-wave fence: LDS ops of one wave execute in program order; this only
// stops the compiler from reordering across the phase boundary. No s_barrier.
#define WFENCE() __builtin_amdgcn_wave_barrier()

// 8-point DFT (symmetric matrix). SGN=-1: forward, SGN=+1: inverse kernel (no 1/N)
template<int SGN>
__device__ __forceinline__ void fft8(float2 a[8]){
    const float r = 0.7071067811865476f;
    const float S = (float)SGN;
    float2 u0 = cadd(a[0], a[4]), u1 = cadd(a[1], a[5]);
    float2 u2 = cadd(a[2], a[6]), u3 = cadd(a[3], a[7]);
    float2 v0 = csub(a[0], a[4]), v1 = csub(a[1], a[5]);
    float2 v2 = csub(a[2], a[6]), v3 = csub(a[3], a[7]);
    v1 = cmul(v1, f2(r, S*r));
    v2 = cmul(v2, f2(0.f, S));
    v3 = cmul(v3, f2(-r, S*r));
    float2 p0 = cadd(u0, u2), p1 = cadd(u1, u3);
    float2 q0 = csub(u0, u2), q1 = cmul(csub(u1, u3), f2(0.f, S));
    a[0] = cadd(p0, p1); a[4] = csub(p0, p1);
    a[2] = cadd(q0, q1); a[6] = csub(q0, q1);
    p0 = cadd(v0, v2); p1 = cadd(v1, v3);
    q0 = csub(v0, v2); q1 = cmul(csub(v1, v3), f2(0.f, S));
    a[1] = cadd(p0, p1); a[5] = csub(p0, p1);
    a[3] = cadd(q0, q1); a[7] = csub(q0, q1);
}

template<int SGN>
__device__ __forceinline__ float2 twd(int idx, float inv){
    float ang = ((float)SGN) * 6.283185307179586f * (inv * (float)idx);
    float s, c;
    __sincosf(ang, &s, &c);
    return f2(c, s);
}

// DIF radix-8^3, 512-pt, per-wave. In: v[q] = x[lane+64q] (natural).
// Out (REGISTERS): v[k2] = X[64*k2 + 8*(lane&7) + (lane>>3)]  (tau-permuted).
template<int SGN>
__device__ void fft512_dif(float2 v[8], float2* buf, int lane){
    fft8<SGN>(v);
    {
        float2 w1 = twd<SGN>(lane, 1.f/512.f);
        float2 w  = f2(1.f, 0.f);
        #pragma unroll
        for (int r = 0; r < 8; ++r){
            buf[pidx(r*64 + lane)] = cmul(v[r], w);
            w = cmul(w, w1);
        }
    }
    WFENCE();
    int rb = (lane >> 3) * 64, t2 = lane & 7;
    float2 y[8];
    #pragma unroll
    for (int q = 0; q < 8; ++q) y[q] = buf[pidx(rb + t2 + 8*q)];
    fft8<SGN>(y);
    WFENCE();
    {
        float2 w2 = twd<SGN>(t2, 1.f/64.f);
        float2 w  = f2(1.f, 0.f);
        #pragma unroll
        for (int r = 0; r < 8; ++r){
            buf[pidx(rb + r*8 + t2)] = cmul(y[r], w);
            w = cmul(w, w2);
        }
    }
    WFENCE();
    int base = rb + t2*8;
    #pragma unroll
    for (int q = 0; q < 8; ++q) v[q] = buf[pidx(base + q)];
    fft8<SGN>(v);
    // v[k2] = X[64k2 + 8*(lane&7) + (lane>>3)] — left tau-permuted in regs
}

// DIT (transposed DIF network): In (REGISTERS): v[k2] = u[64*k2 + 8*(lane&7) + (lane>>3)].
// Out: v[q] = X[lane + 64q] (natural).
template<int SGN>
__device__ void fft512_dit(float2 v[8], float2* buf, int lane){
    int rb = (lane >> 3) * 64, t2 = lane & 7;
    fft8<SGN>(v);
    int base = rb + t2*8;
    #pragma unroll
    for (int q = 0; q < 8; ++q) buf[pidx(base + q)] = v[q];
    WFENCE();
    float2 y[8];
    #pragma unroll
    for (int r = 0; r < 8; ++r) y[r] = buf[pidx(rb + r*8 + t2)];
    {
        float2 w2 = twd<SGN>(t2, 1.f/64.f);
        float2 w  = f2(1.f, 0.f);
        #pragma unroll
        for (int r = 0; r < 8; ++r){
            y[r] = cmul(y[r], w);
            w = cmul(w, w2);
        }
    }
    fft8<SGN>(y);
    WFENCE();
    #pragma unroll
    for (int q = 0; q < 8; ++q) buf[pidx(rb + t2 + 8*q)] = y[q];
    WFENCE();
    #pragma unroll
    for (int r = 0; r < 8; ++r) v[r] = buf[pidx(r*64 + lane)];
    {
        float2 w1 = twd<SGN>(lane, 1.f/512.f);
        float2 w  = f2(1.f, 0.f);
        #pragma unroll
        for (int r = 0; r < 8; ++r){
            v[r] = cmul(v[r], w);
            w = cmul(w, w1);
        }
    }
    fft8<SGN>(v);
}

// K1: temp[kj] = row-IFFT( x_hat * psi_hat[kj] ) stored fp16 tau-permuted;
// also emits psi2 = |psi|^2 as fp16 (natural order) for the GEMM.
__global__ __launch_bounds__(256, 6)
void k_mulrow(const float2* __restrict__ xh, const float* __restrict__ pr,
              const float* __restrict__ pi, __half2* __restrict__ temp,
              __half* __restrict__ psi2h){
    __shared__ float2 lds[4][548];
    int wave = threadIdx.x >> 6, lane = threadIdx.x & 63;
    int img  = blockIdx.x >> 7;
    int row  = ((blockIdx.x & 127) << 2) | wave;
    size_t boff = (size_t)img * NNe + (size_t)row * Nn;
    const float2* xr = xh + (size_t)row * Nn;
    float2 v[8];
    #pragma unroll
    for (int q = 0; q < 8; ++q){
        int x = lane + 64*q;
        float2 xv = xr[x];
        float2 pv = f2(pr[boff + x], pi[boff + x]);
        psi2h[boff + x] = __float2half_rn(pv.x*pv.x + pv.y*pv.y);
        v[q] = cmul(xv, pv);
    }
    fft512_dif<1>(v, lds[wave], lane);
    __half2* outp = temp + boff;
    #pragma unroll
    for (int q = 0; q < 8; ++q) outp[64*q + lane] = __floats2half2_rn(v[q].x, v[q].y);
}

// K2 (fused): col-IFFT + modulus + col-FFT, in place on fp16 temp.
// 8-column tiles, 8 waves (one column per wave); 2 block barriers.
__global__ __launch_bounds__(512, 6)
void k_colfused(__half2* __restrict__ temp){
    __shared__ float2 tile[8 * CST];
    int img = blockIdx.x >> 6;
    int x0  = (blockIdx.x & 63) << 3;
    __half2* srcH = temp + (size_t)img * NNe + x0;
    for (int i = threadIdx.x; i < 1024; i += 512){
        int yy = i >> 1, c4 = (i & 1) << 2;
        uint4 u = *(const uint4*)&srcH[(size_t)yy * Nn + c4];
        tile[(c4+0)*CST + pidx(yy)] = __half22float2(*(__half2*)&u.x);
        tile[(c4+1)*CST + pidx(yy)] = __half22float2(*(__half2*)&u.y);
        tile[(c4+2)*CST + pidx(yy)] = __half22float2(*(__half2*)&u.z);
        tile[(c4+3)*CST + pidx(yy)] = __half22float2(*(__half2*)&u.w);
    }
    __syncthreads();
    int wave = threadIdx.x >> 6, lane = threadIdx.x & 63;
    const float sc = 3.814697265625e-06f;   // 1/NN (ifft2 normalization)
    {
        float2* buf = &tile[wave * CST];
        float2 v[8];
        #pragma unroll
        for (int q = 0; q < 8; ++q) v[q] = buf[pidx(lane + 64*q)];
        fft512_dif<1>(v, buf, lane);        // col IFFT -> tau-permuted regs
        #pragma unroll
        for (int q = 0; q < 8; ++q){        // modulus (pointwise, order-free)
            float re = v[q].x * sc, im = v[q].y * sc;
            v[q] = f2(sqrtf(re*re + im*im + 1e-8f), 0.f);
        }
        WFENCE();
        fft512_dit<-1>(v, buf, lane);       // col FFT -> natural regs
        #pragma unroll
        for (int q = 0; q < 8; ++q) buf[pidx(lane + 64*q)] = v[q];
    }
    __syncthreads();
    for (int i = threadIdx.x; i < 1024; i += 512){
        int yy = i >> 1, c4 = (i & 1) << 2;
        uint4 u;
        float2 a0 = tile[(c4+0)*CST + pidx(yy)];
        float2 a1 = tile[(c4+1)*CST + pidx(yy)];
        float2 a2 = tile[(c4+2)*CST + pidx(yy)];
        float2 a3 = tile[(c4+3)*CST + pidx(yy)];
        *(__half2*)&u.x = __floats2half2_rn(a0.x, a0.y);
        *(__half2*)&u.y = __floats2half2_rn(a1.x, a1.y);
        *(__half2*)&u.z = __floats2half2_rn(a2.x, a2.y);
        *(__half2*)&u.w = __floats2half2_rn(a3.x, a3.y);
        *(uint4*)&srcH[(size_t)yy * Nn + c4] = u;
    }
}

// K3: row FFT + |.|^2 -> power (fp16, scaled by 2^-8; DC ~8e5*2^-8=3.2e3 fits).
__global__ __launch_bounds__(256, 6)
void k_rowpow(const __half2* __restrict__ temp, __half* __restrict__ powerh){
    __shared__ float2 lds[4][548];
    int wave = threadIdx.x >> 6, lane = threadIdx.x & 63;
    int img  = blockIdx.x >> 7;
    int row  = ((blockIdx.x & 127) << 2) | wave;
    const __half2* src = temp + (size_t)img * NNe + (size_t)row * Nn;
    float2 v[8];
    #pragma unroll
    for (int q = 0; q < 8; ++q) v[q] = __half22float2(src[64*q + lane]);
    fft512_dit<-1>(v, lds[wave], lane);
    __half* dst = powerh + (size_t)img * NNe + (size_t)row * Nn;
    #pragma unroll
    for (int q = 0; q < 8; ++q)
        dst[lane + 64*q] = __float2half_rn((v[q].x*v[q].x + v[q].y*v[q].y) * 0.00390625f);
}

// s0 partials
__global__ __launch_bounds__(256)
void k_s0(const float2* __restrict__ xh, const float* __restrict__ phr,
          const float* __restrict__ phii, float* __restrict__ part){
    int gid = blockIdx.x*256 + threadIdx.x;
    float acc = 0.f;
    for (int n = gid; n < NNe; n += 256*256){
        float2 x = xh[n];
        float a = phr[n], b = phii[n];
        acc += (x.x*x.x + x.y*x.y) * (a*a + b*b);
    }
    #pragma unroll
    for (int o = 32; o > 0; o >>= 1) acc += __shfl_down(acc, o, 64);
    __shared__ float wsum[4];
    int wave = threadIdx.x >> 6, lane = threadIdx.x & 63;
    if (lane == 0) wsum[wave] = acc;
    __syncthreads();
    if (threadIdx.x == 0) part[blockIdx.x] = wsum[0]+wsum[1]+wsum[2]+wsum[3];
}

// K5: C[48][49] = power[48][NN] x {psi2, phi2}[NN][49]; power+psi2 from fp16.
__global__ __launch_bounds__(128)
void k_gemm(const __half* __restrict__ powerh, const __half* __restrict__ psi2h,
            const float* __restrict__ phr, const float* __restrict__ phii,
            float* __restrict__ partC){
    __shared__ __align__(16) float P[2][48][68];
    __shared__ __align__(16) float W[2][56][68];
    int wave = threadIdx.x >> 6, lane = threadIdx.x & 63;
    float (*Pw)[68] = P[wave];
    float (*Ww)[68] = W[wave];
    int gw = blockIdx.x*2 + wave;           // 0..1023
    int lm = lane >> 3, lw = lane & 7;
    float acc[6][7] = {};
    #pragma unroll
    for (int r = 49; r < 56; ++r){          // zero W pad rows once
        Ww[r][lane] = 0.f;
        if (lane < 4) Ww[r][64 + lane] = 0.f;
    }
    int n0 = gw * 256;
    for (int st = 0; st < 4; ++st){
        int nb = n0 + st*64;
        __syncthreads();
        #pragma unroll
        for (int rr = 0; rr < 12; ++rr){
            int row = rr*4 + (lane >> 4);
            int c4  = (lane & 15) * 4;
            size_t off = (size_t)row*NNe + nb + c4;
            const __half2* p2 = (const __half2*)&powerh[off];
            float2 f0 = __half22float2(p2[0]);
            float2 f1 = __half22float2(p2[1]);
            *(float4*)&Pw[row][c4] = make_float4(f0.x, f0.y, f1.x, f1.y);
        }
        #pragma unroll
        for (int rr = 0; rr < 12; ++rr){
            int row = rr*4 + (lane >> 4);
            int c4  = (lane & 15) * 4;
            size_t off = (size_t)row*NNe + nb + c4;
            const __half2* p2 = (const __half2*)&psi2h[off];
            float2 f0 = __half22float2(p2[0]);
            float2 f1 = __half22float2(p2[1]);
            *(float4*)&Ww[row][c4] = make_float4(f0.x, f0.y, f1.x, f1.y);
        }
        if (lane < 16){
            int c4 = lane * 4;
            float4 a = *(const float4*)&phr[nb + c4];
            float4 b = *(const float4*)&phii[nb + c4];
            float4 w4;
            w4.x = a.x*a.x + b.x*b.x; w4.y = a.y*a.y + b.y*b.y;
            w4.z = a.z*a.z + b.z*b.z; w4.w = a.w*a.w + b.w*b.w;
            *(float4*)&Ww[48][c4] = w4;
        }
        __syncthreads();
        #pragma unroll 2
        for (int nn = 0; nn < 64; nn += 4){
            float4 pa[6], wb[7];
            #pragma unroll
            for (int i = 0; i < 6; ++i) pa[i] = *(const float4*)&Pw[lm + 8*i][nn];
            #pragma unroll
            for (int j = 0; j < 7; ++j) wb[j] = *(const float4*)&Ww[lw + 8*j][nn];
            #pragma unroll
            for (int i = 0; i < 6; ++i)
                #pragma unroll
                for (int j = 0; j < 7; ++j){
                    float s = acc[i][j];
                    s = fmaf(pa[i].x, wb[j].x, s);
                    s = fmaf(pa[i].y, wb[j].y, s);
                    s = fmaf(pa[i].z, wb[j].z, s);
                    s = fmaf(pa[i].w, wb[j].w, s);
                    acc[i][j] = s;
                }
        }
    }
    float* outp = partC + (size_t)gw * 2400;
    #pragma unroll
    for (int i = 0; i < 6; ++i)
        #pragma unroll
        for (int j = 0; j < 7; ++j){
            int m = lm + 8*i, wc = lw + 8*j;
            if (wc < 49) outp[m*50 + wc] = acc[i][j];
        }
}

// reduce 1024 partial C slices -> CF[2400], two parallel stages
// stage 1: grid (38,16); block sums 64 slices (16 per wave, unrolled independent loads)
__global__ __launch_bounds__(256)
void k_redc1(const float* __restrict__ partC, float* __restrict__ partC2){
    __shared__ float red[4][64];
    int es = threadIdx.x & 63, wave = threadIdx.x >> 6;
    int e = blockIdx.x*64 + es;
    int b0 = blockIdx.y*64 + wave*16;
    float s = 0.f;
    if (e < 2400){
        #pragma unroll
        for (int u = 0; u < 16; ++u) s += partC[(size_t)(b0+u)*2400 + e];
    }
    red[wave][es] = s;
    __syncthreads();
    if (wave == 0 && e < 2400)
        partC2[(size_t)blockIdx.y*2400 + e] = red[0][es]+red[1][es]+red[2][es]+red[3][es];
}
// stage 2: grid 38; sum the 16 stage-1 slices
__global__ __launch_bounds__(256)
void k_redc2(const float* __restrict__ partC2, float* __restrict__ CF){
    __shared__ float red[4][64];
    int es = threadIdx.x & 63, wave = threadIdx.x >> 6;
    int e = blockIdx.x*64 + es;
    float s = 0.f;
    if (e < 2400){
        #pragma unroll
        for (int u = 0; u < 4; ++u) s += partC2[(size_t)(wave*4+u)*2400 + e];
    }
    red[wave][es] = s;
    __syncthreads();
    if (wave == 0 && e < 2400)
        CF[e] = red[0][es]+red[1][es]+red[2][es]+red[3][es];
}

// final: s0 + assemble 1009-element output in torch-loop concatenation order.
// SC0: scale for s0; SCC: scale for CF entries (includes 2^8 power-descale).
__global__ __launch_bounds__(256)
void k_final(const float* __restrict__ CF, const float* __restrict__ partS0,
             float* __restrict__ outp, float SC0, float SCC){
    __shared__ float ssum[4];
    int tid = threadIdx.x, wave = tid >> 6, lane = tid & 63;
    float a = partS0[tid];
    #pragma unroll
    for (int o = 32; o > 0; o >>= 1) a += __shfl_down(a, o, 64);
    if (lane == 0) ssum[wave] = a;
    __syncthreads();
    if (tid == 0) outp[0] = SC0 * (ssum[0]+ssum[1]+ssum[2]+ssum[3]);
    int off = 1;
    for (int i = 0; i < 6; ++i){
        if (tid < 8) outp[off + tid] = SCC * CF[(tid*6 + i)*50 + 48];   // a[:, i]
        off += 8;
        if (i < 5){
            int nj = 5 - i, cnt = 64 * nj;
            for (int p = tid; p < cnt; p += 256){
                int j2 = p % nj;
                int km = p / nj;
                int m = km & 7, k = km >> 3;
                outp[off + p] = SCC * CF[(k*6 + i)*50 + m*6 + (i + 1 + j2)];
            }
            off += cnt;
        }
    }
}

extern "C" void kernel_launch(void* const* d_in, const int* in_sizes, int n_in,
                              void* d_out, int out_size, void* d_ws, size_t ws_size,
                              hipStream_t stream){
    (void)in_sizes; (void)n_in; (void)out_size; (void)ws_size;
    const float2* xh  = (const float2*)d_in[0];
    const float*  phr = (const float*)d_in[1];
    const float*  phi_= (const float*)d_in[2];
    const float*  psr = (const float*)d_in[3];
    const float*  psi_= (const float*)d_in[4];
    float* outp = (float*)d_out;
    float* ws   = (float*)d_ws;

    // ws layout (f32 units): power(half)[48NN->24NN] | partC[1024*2400] | partC2[16*2400] |
    //                        s0[256] | CF[2400] | temp(half2)[48NN] | psi2(half)[24NN]
    size_t o_power = 0;
    size_t o_partC = o_power + (size_t)24 * NNe;
    size_t o_pC2   = o_partC + (size_t)1024 * 2400;
    size_t o_s0    = o_pC2 + (size_t)16 * 2400;
    size_t o_CF    = o_s0 + 256;
    size_t o_temp  = o_CF + 2400;
    size_t o_psi2  = o_temp + (size_t)48 * NNe;
    __half*  powerh= (__half*)(ws + o_power);
    float*   partC = ws + o_partC;
    float*   partC2= ws + o_pC2;
    float*   ps0   = ws + o_s0;
    float*   CF    = ws + o_CF;
    __half2* temp  = (__half2*)(ws + o_temp);
    __half*  psi2h = (__half*)(ws + o_psi2);

    const double INVd = 1.0 / (4.0 * 3.14159265358979323846 * 3.14159265358979323846);
    const float SC0 = (float)(INVd / (double)NNe);          // INV / NN (s0 path)
    const float SCC = (float)(INVd / (double)NNe * 256.0);  // + 2^8 power descale

    k_s0<<<dim3(256), dim3(256), 0, stream>>>(xh, phr, phi_, ps0);
    k_mulrow<<<dim3(48*128), dim3(256), 0, stream>>>(xh, psr, psi_, temp, psi2h);
    k_colfused<<<dim3(48*64), dim3(512), 0, stream>>>(temp);
    k_rowpow<<<dim3(48*128), dim3(256), 0, stream>>>(temp, powerh);
    k_gemm<<<dim3(512), dim3(128), 0, stream>>>(powerh, psi2h, phr, phi_, partC);
    k_redc1<<<dim3(38, 16), dim3(256), 0, stream>>>(partC, partC2);
    k_redc2<<<dim3(38), dim3(256), 0, stream>>>(partC2, CF);
    k_final<<<dim3(1), dim3(256), 0, stream>>>(CF, ps0, outp, SC0, SCC);
}